// Round 3
// baseline (50394.702 us; speedup 1.0000x reference)
//
#include <hip/hip_runtime.h>
#include <math.h>

#define TT 833          // output timesteps
#define GDIM 1024       // 4*H gates
// LDS carve for recur_k (floats): weights 32768 + hbuf 512 + psum 256 + cst 2048
#define RECUR_SMEM_FLOATS 35584

__device__ __forceinline__ float sigm(float x){ return 1.f/(1.f+expf(-x)); }

// Chunk barrier. Fast path (all 8 slices co-resident on one XCD, runtime-verified):
// h goes through the shared XCD L2 (plain stores drained by the vmcnt(0) that
// __syncthreads emits; sc0 loads bypass L1). Signal = relaxed fetch_add (executes at
// the device coherence point). Poll = relaxed atomic RMW with an asm-opaque zero —
// a load-poll can spin on a stale local-L2 copy (round-2 lesson: 3.2x regression),
// an RMW always executes at the coherence point. No cache wb/inv anywhere.
// Fallback: round-1 heavyweight release/acquire (correct for any block->XCD mapping).
__device__ __forceinline__ void chunk_barrier(int* cnt, int target, int safe){
  if (safe){
    __hip_atomic_fetch_add(cnt, 1, __ATOMIC_RELAXED, __HIP_MEMORY_SCOPE_AGENT);
    int zr; asm volatile("v_mov_b32 %0, 0" : "=v"(zr));
    while (__hip_atomic_fetch_add(cnt, zr, __ATOMIC_RELAXED, __HIP_MEMORY_SCOPE_AGENT) < target) {}
  } else {
    __threadfence();
    __hip_atomic_fetch_add(cnt, 1, __ATOMIC_RELEASE, __HIP_MEMORY_SCOPE_AGENT);
    while (__hip_atomic_load(cnt, __ATOMIC_ACQUIRE, __HIP_MEMORY_SCOPE_AGENT) < target) {}
  }
}

// ---------------- level smoothing scan ----------------
__global__ void levels_k(const float* __restrict__ train, const float* __restrict__ ism,
                         float* __restrict__ levs){
  int b = threadIdx.x;
  if (b >= 32) return;
  float a = 1.f/(1.f+expf(-ism[0]));
  const float* tr = train + b*1024;
  float* lv = levs + b*1024;
  float lev = fmaxf(tr[0], 0.1f);
  lv[0] = lev;
  for (int t = 1; t < 1024; ++t){
    lev = fmaxf(a*tr[t] + (1.f-a)*lev, 0.1f);
    lv[t] = lev;
  }
}

// ---------------- normalized input windows x0[t*32+b][168] ----------------
__global__ void win_x_k(const float* __restrict__ train, const float* __restrict__ levs,
                        float* __restrict__ x0){
  int idx = blockIdx.x*256 + threadIdx.x;   // exactly 833*32*168
  int i = idx % 168;
  int r = idx / 168;       // t*32+b
  int b = r & 31;
  int t = r >> 5;
  x0[idx] = train[b*1024 + t + i] / levs[b*1024 + t + 167];
}

// ---------------- out_win -> d_out second half ----------------
__global__ void win_out_k(const float* __restrict__ train, const float* __restrict__ levs,
                          float* __restrict__ ow){
  int idx = blockIdx.x*256 + threadIdx.x;   // exactly 833*32*24
  int o = idx % 24;
  int r = idx / 24;
  int b = r & 31;
  int t = r >> 5;
  ow[idx] = train[b*1024 + 168 + t + o] / levs[b*1024 + t + 167];
}

// ---------------- whh[1024][256] -> whhT[256][1024] ----------------
__global__ void transp_k(const float* __restrict__ w, float* __restrict__ wt){
  int idx = blockIdx.x*256 + threadIdx.x;
  if (idx >= 1024*256) return;
  int k = idx >> 10, g = idx & 1023;
  wt[idx] = w[g*256 + k];
}

// ---------------- generic fp32 GEMM: C[m][n] = A[map(m)][:K] . W[n][:K] + b1 (+b2), opt tanh
__global__ __launch_bounds__(256) void proj_gemm(
    const float* __restrict__ A, const float* __restrict__ W,
    const float* __restrict__ b1, const float* __restrict__ b2,
    float* __restrict__ C, int Mout, int K, int N, int dil, int act)
{
  __shared__ float As[16][68];
  __shared__ float Bs[16][68];
  int tid = threadIdx.x;
  int tx = tid & 15, ty = tid >> 4;
  int m0 = blockIdx.y << 6, n0 = blockIdx.x << 6;
  int amap[4];
  #pragma unroll
  for (int i = 0; i < 4; ++i){
    int m = m0 + (tid >> 4) + i*16;
    int row;
    if (dil == 0){ row = (m < Mout) ? m : -1; }
    else {
      int rows = dil << 5;
      int j = m / rows;
      int q = m - j*rows;
      int t = j*dil + (q >> 5);
      row = (t < TT) ? ((t << 5) + (q & 31)) : -1;
    }
    amap[i] = row;
  }
  float acc[4][4] = {{0.f,0.f,0.f,0.f},{0.f,0.f,0.f,0.f},{0.f,0.f,0.f,0.f},{0.f,0.f,0.f,0.f}};
  int nkt = (K + 15) >> 4;
  for (int kt = 0; kt < nkt; ++kt){
    int kk = (kt << 4) + (tid & 15);
    bool kin = kk < K;
    #pragma unroll
    for (int i = 0; i < 4; ++i){
      int ml = (tid >> 4) + i*16;
      As[tid & 15][ml] = (kin && amap[i] >= 0) ? A[(size_t)amap[i]*K + kk] : 0.f;
      Bs[tid & 15][ml] = kin ? W[(size_t)(n0 + ml)*K + kk] : 0.f;
    }
    __syncthreads();
    #pragma unroll
    for (int k = 0; k < 16; ++k){
      float4 av = *reinterpret_cast<const float4*>(&As[k][ty << 2]);
      float4 bv = *reinterpret_cast<const float4*>(&Bs[k][tx << 2]);
      float a4[4] = {av.x, av.y, av.z, av.w};
      float b4[4] = {bv.x, bv.y, bv.z, bv.w};
      #pragma unroll
      for (int i = 0; i < 4; ++i)
        #pragma unroll
        for (int j = 0; j < 4; ++j)
          acc[i][j] = fmaf(a4[i], b4[j], acc[i][j]);
    }
    __syncthreads();
  }
  #pragma unroll
  for (int i = 0; i < 4; ++i){
    int m = m0 + (ty << 2) + i;
    if (m >= Mout) continue;
    #pragma unroll
    for (int j = 0; j < 4; ++j){
      int n = n0 + (tx << 2) + j;
      float v = acc[i][j] + b1[n] + (b2 ? b2[n] : 0.f);
      if (act) v = tanhf(v);
      C[(size_t)m*N + n] = v;
    }
  }
}

// ---------------- persistent dilated-LSTM recurrence ----------------
// grid = 256 = 32 chunks x 8 slices; slice owns h[slice*32 .. +32) i.e. 128 gate rows.
__global__ __launch_bounds__(256,1) void recur_k(
    const float* __restrict__ Gin, const float* __restrict__ whhT,
    float* __restrict__ hstate, float* __restrict__ out, const float* __restrict__ res,
    int* __restrict__ cntbase, int* __restrict__ xcdtab,
    int nsteps, int R /* == dilation; rows = 32*R */)
{
  extern __shared__ float sm[];
  float2* wl = reinterpret_cast<float2*>(sm);   // [k2][128] float2 (k-major pairs)
  float* hbuf = sm + 32768;                     // 512 (2 rows x 256)
  float* psum = sm + 33280;                     // 256
  float* cst  = sm + 33536;                     // R*32 cell states
  __shared__ int s_safe;
  const int tid = threadIdx.x;
  const int chunk = blockIdx.x & 31;
  const int slice = blockIdx.x >> 5;
  const int rows = R << 5;
  const int hsz = rows << 8;
  int* cnt = cntbase + chunk*32;

  if (tid == 0){
    int xid;
    asm volatile("s_getreg_b32 %0, hwreg(HW_REG_XCC_ID)" : "=s"(xid));
    __hip_atomic_store(&xcdtab[blockIdx.x], xid, __ATOMIC_RELAXED, __HIP_MEMORY_SCOPE_AGENT);
  }

  for (int e = tid; e < 16384; e += 256){
    int gg = e & 127, k2 = e >> 7;
    int gr = ((gg >> 5) << 8) + (slice << 5) + (gg & 31);   // i/f/g/o gate row
    wl[e] = make_float2(whhT[(size_t)(k2*2)*GDIM + gr], whhT[(size_t)(k2*2+1)*GDIM + gr]);
  }
  for (int e = tid; e < (R << 5); e += 256) cst[e] = 0.f;
  for (int e = tid; e < (R << 5); e += 256){
    int r = e >> 5, j = e & 31;
    hstate[((chunk*R + r) << 8) + (slice << 5) + j] = 0.f;
  }
  __syncthreads();
  // heavyweight init barrier (once): publishes zeroed hstate + xcdtab
  if (tid == 0){
    __threadfence();
    __hip_atomic_fetch_add(cnt, 1, __ATOMIC_RELEASE, __HIP_MEMORY_SCOPE_AGENT);
    while (__hip_atomic_load(cnt, __ATOMIC_ACQUIRE, __HIP_MEMORY_SCOPE_AGENT) < 8) {}
    int x0v = __hip_atomic_load(&xcdtab[chunk], __ATOMIC_RELAXED, __HIP_MEMORY_SCOPE_AGENT);
    int ok = 1;
    for (int s2 = 1; s2 < 8; ++s2){
      int v = __hip_atomic_load(&xcdtab[(s2 << 5) + chunk], __ATOMIC_RELAXED, __HIP_MEMORY_SCOPE_AGENT);
      ok &= (v == x0v);
    }
    s_safe = ok;
  }
  __syncthreads();
  const int safe = s_safe;

  if (R == 1){
    int gg = tid & 127, half = tid >> 7;
    int gr = ((gg >> 5) << 8) + (slice << 5) + (gg & 31);
    float gcur = (half == 0) ? Gin[(size_t)chunk*GDIM + gr] : 0.f;
    for (int step = 0; step < nsteps; ++step){
      const int rp = step & 1;
      const float* hsr = hstate + (size_t)rp*hsz;
      float* hsw = hstate + (size_t)(1-rp)*hsz;
      hbuf[tid] = __hip_atomic_load(&hsr[(chunk << 8) + tid], __ATOMIC_RELAXED, __HIP_MEMORY_SCOPE_AGENT);
      __syncthreads();
      {
        float acc = (half == 0) ? gcur : 0.f;
        const float2* h2 = reinterpret_cast<const float2*>(hbuf) + (half << 6);
        const float2* w2 = wl + ((half << 6) << 7);
        #pragma unroll 8
        for (int k2 = 0; k2 < 64; ++k2){
          float2 wv = w2[(k2 << 7) + gg];
          float2 hv = h2[k2];
          acc = fmaf(wv.x, hv.x, acc);
          acc = fmaf(wv.y, hv.y, acc);
        }
        psum[tid] = acc;
      }
      // prefetch next step's Gin (off critical path)
      float gnext = 0.f;
      if (half == 0 && step + 1 < nsteps)
        gnext = Gin[(size_t)(((step + 1) << 5) + chunk)*GDIM + gr];
      __syncthreads();
      if (tid < 32){
        float iv = psum[tid]      + psum[tid + 128];
        float fv = psum[tid + 32] + psum[tid + 160];
        float gv = psum[tid + 64] + psum[tid + 192];
        float ov = psum[tid + 96] + psum[tid + 224];
        float c = cst[tid];
        c = sigm(fv)*c + sigm(iv)*tanhf(gv);
        float h = sigm(ov)*tanhf(c);
        cst[tid] = c;
        hsw[(chunk << 8) + (slice << 5) + tid] = h;
        size_t oi = (size_t)((step << 5) + chunk)*256 + (slice << 5) + tid;
        float v = h;
        if (res) v += res[oi];
        out[oi] = v;
      }
      __syncthreads();   // drains hsw writes (vmcnt(0) before s_barrier)
      if (step + 1 < nsteps){
        if (tid == 0) chunk_barrier(cnt, (step + 2) << 3, safe);
        __syncthreads();
      }
      gcur = gnext;
    }
  } else {
    for (int step = 0; step < nsteps; ++step){
      const int rp = step & 1;
      const float* hsr = hstate + (size_t)rp*hsz;
      float* hsw = hstate + (size_t)(1-rp)*hsz;
      for (int r0 = 0; r0 < R; r0 += 2){
        for (int e = tid; e < 512; e += 256)
          hbuf[e] = __hip_atomic_load(&hsr[((chunk*R + r0 + (e >> 8)) << 8) + (e & 255)],
                                      __ATOMIC_RELAXED, __HIP_MEMORY_SCOPE_AGENT);
        __syncthreads();
        {
          int gg = tid & 127, rr = tid >> 7;
          int q = chunk*R + r0 + rr;
          int gr = ((gg >> 5) << 8) + (slice << 5) + (gg & 31);
          float acc = Gin[(size_t)(step*rows + q)*GDIM + gr];
          const float2* h2 = reinterpret_cast<const float2*>(hbuf) + (rr << 7);
          #pragma unroll 8
          for (int k2 = 0; k2 < 128; ++k2){
            float2 wv = wl[(k2 << 7) + gg];
            float2 hv = h2[k2];
            acc = fmaf(wv.x, hv.x, acc);
            acc = fmaf(wv.y, hv.y, acc);
          }
          psum[tid] = acc;
        }
        __syncthreads();
        if (tid < 64){
          int rr = tid >> 5, j = tid & 31;
          int q = chunk*R + r0 + rr;
          float iv = psum[(rr << 7) + j];
          float fv = psum[(rr << 7) + 32 + j];
          float gv = psum[(rr << 7) + 64 + j];
          float ov = psum[(rr << 7) + 96 + j];
          float c = cst[((r0 + rr) << 5) + j];
          c = sigm(fv)*c + sigm(iv)*tanhf(gv);
          float h = sigm(ov)*tanhf(c);
          cst[((r0 + rr) << 5) + j] = c;
          hsw[(q << 8) + (slice << 5) + j] = h;
          int p = q >> 5, b = q & 31;
          int t = step*R + p;
          if (t < TT){
            size_t oi = (size_t)((t << 5) + b)*256 + (slice << 5) + j;
            float v = h;
            if (res) v += res[oi];
            out[oi] = v;
          }
        }
        __syncthreads();
      }
      if (step + 1 < nsteps){
        if (tid == 0) chunk_barrier(cnt, (step + 2) << 3, safe);
        __syncthreads();
      }
    }
  }
}

// ---------------- scoring head: pred[m][24] = xt[m][:] . sc_w[n][:] + sc_b ----------------
__global__ __launch_bounds__(256) void sc_head(const float* __restrict__ xt, const float* __restrict__ w,
                        const float* __restrict__ bias, float* __restrict__ outp, int M){
  __shared__ float arow[8][256];
  int m0 = blockIdx.x << 3;
  int tid = threadIdx.x;
  #pragma unroll
  for (int i = 0; i < 8; ++i){
    int e = tid + (i << 8);
    int r = e >> 8, k = e & 255;
    arow[r][k] = (m0 + r < M) ? xt[(size_t)(m0 + r)*256 + k] : 0.f;
  }
  __syncthreads();
  int r = tid >> 5, n = tid & 31;
  if (n < 24 && (m0 + r) < M){
    float acc = bias[n];
    const float* wr = w + n*256;
    #pragma unroll 8
    for (int k = 0; k < 256; ++k) acc = fmaf(arow[r][k], wr[k], acc);
    outp[(size_t)(m0 + r)*24 + n] = acc;
  }
}

extern "C" void kernel_launch(void* const* d_in, const int* in_sizes, int n_in,
                              void* d_out, int out_size, void* d_ws, size_t ws_size,
                              hipStream_t stream){
  const float* train = (const float*)d_in[0];
  const float* ism   = (const float*)d_in[4];
  const float* wih[4] = {(const float*)d_in[5], (const float*)d_in[9], (const float*)d_in[13], (const float*)d_in[17]};
  const float* whh[4] = {(const float*)d_in[6], (const float*)d_in[10], (const float*)d_in[14], (const float*)d_in[18]};
  const float* bih[4] = {(const float*)d_in[7], (const float*)d_in[11], (const float*)d_in[15], (const float*)d_in[19]};
  const float* bhh[4] = {(const float*)d_in[8], (const float*)d_in[12], (const float*)d_in[16], (const float*)d_in[20]};
  const float* nl_w = (const float*)d_in[21];
  const float* nl_b = (const float*)d_in[22];
  const float* sc_w = (const float*)d_in[23];
  const float* sc_b = (const float*)d_in[24];
  float* out = (float*)d_out;

  float* ws = (float*)d_ws;
  size_t off = 0;
  float* levs = ws + off;   off += 32768;
  int*   cnt  = (int*)(ws + off); off += 4096;          // 4 layers * 32 chunks * 32-int stride
  int*   xcdtab = (int*)(ws + off); off += 256;
  float* whhT = ws + off;   off += (size_t)4*262144;
  float* hstate = ws + off; off += (size_t)2*2048*256;
  float* x0 = ws + off;     off += (size_t)26656*168;
  float* G  = ws + off;     off += (size_t)28672*1024;
  float* h0 = ws + off;     off += (size_t)26656*256;
  float* h1 = ws + off;     off += (size_t)26656*256;
  float* h2 = ws + off;     off += (size_t)26656*256;
  (void)ws_size; (void)in_sizes; (void)n_in; (void)out_size;

  hipMemsetAsync(cnt, 0, 4096*sizeof(int), stream);
  levels_k<<<1, 64, 0, stream>>>(train, ism, levs);
  win_x_k<<<17493, 256, 0, stream>>>(train, levs, x0);
  win_out_k<<<2499, 256, 0, stream>>>(train, levs, out + 639744);
  for (int l = 0; l < 4; ++l)
    transp_k<<<1024, 256, 0, stream>>>(whh[l], whhT + (size_t)l*262144);

  const int SMEM = RECUR_SMEM_FLOATS*4;
  hipFuncSetAttribute(reinterpret_cast<const void*>(recur_k),
                      hipFuncAttributeMaxDynamicSharedMemorySize, SMEM);

  // layer 0 (d=1): 833 steps, rows=32
  proj_gemm<<<dim3(16,417), 256, 0, stream>>>(x0, wih[0], bih[0], bhh[0], G, 26656, 168, 1024, 0, 0);
  recur_k<<<256, 256, SMEM, stream>>>(G, whhT + 0, hstate, h0, nullptr, cnt + 0, xcdtab, 833, 1);
  // layer 1 (d=4): 209 steps, rows=128
  proj_gemm<<<dim3(16,418), 256, 0, stream>>>(h0, wih[1], bih[1], bhh[1], G, 26752, 256, 1024, 4, 0);
  recur_k<<<256, 256, SMEM, stream>>>(G, whhT + 262144, hstate, h1, nullptr, cnt + 1024, xcdtab, 209, 4);
  // layer 2 (d=16): 53 steps, rows=512
  proj_gemm<<<dim3(16,424), 256, 0, stream>>>(h1, wih[2], bih[2], bhh[2], G, 27136, 256, 1024, 16, 0);
  recur_k<<<256, 256, SMEM, stream>>>(G, whhT + 2*262144, hstate, h2, nullptr, cnt + 2048, xcdtab, 53, 16);
  // layer 3 (d=64): 14 steps, rows=2048, residual = h1 (group-1 skip), out overwrites h2 (xf)
  proj_gemm<<<dim3(16,448), 256, 0, stream>>>(h2, wih[3], bih[3], bhh[3], G, 28672, 256, 1024, 64, 0);
  recur_k<<<256, 256, SMEM, stream>>>(G, whhT + 3*262144, hstate, h2, h1, cnt + 3072, xcdtab, 14, 64);
  // nonlinear dense: xt = tanh(xf @ nl_w.T + nl_b)  (reuse h0)
  proj_gemm<<<dim3(4,417), 256, 0, stream>>>(h2, nl_w, nl_b, nullptr, h0, 26656, 256, 256, 0, 1);
  // scoring head -> pred (first half of d_out)
  sc_head<<<3332, 256, 0, stream>>>(h0, sc_w, sc_b, out, 26656);
}

// Round 4
// 7083.519 us; speedup vs baseline: 7.1144x; 7.1144x over previous
//
#include <hip/hip_runtime.h>
#include <hip/hip_fp16.h>
#include <math.h>

#define TT 833          // output timesteps
#define GDIM 1024       // 4*H gates

__device__ __forceinline__ float sigm(float x){ return 1.f/(1.f+expf(-x)); }

// ---------------- level smoothing scan ----------------
__global__ void levels_k(const float* __restrict__ train, const float* __restrict__ ism,
                         float* __restrict__ levs){
  int b = threadIdx.x;
  if (b >= 32) return;
  float a = 1.f/(1.f+expf(-ism[0]));
  const float* tr = train + b*1024;
  float* lv = levs + b*1024;
  float lev = fmaxf(tr[0], 0.1f);
  lv[0] = lev;
  for (int t = 1; t < 1024; ++t){
    lev = fmaxf(a*tr[t] + (1.f-a)*lev, 0.1f);
    lv[t] = lev;
  }
}

// ---------------- normalized input windows x0[t*32+b][168] ----------------
__global__ void win_x_k(const float* __restrict__ train, const float* __restrict__ levs,
                        float* __restrict__ x0){
  int idx = blockIdx.x*256 + threadIdx.x;   // exactly 833*32*168
  int i = idx % 168;
  int r = idx / 168;       // t*32+b
  int b = r & 31;
  int t = r >> 5;
  x0[idx] = train[b*1024 + t + i] / levs[b*1024 + t + 167];
}

// ---------------- out_win -> d_out second half ----------------
__global__ void win_out_k(const float* __restrict__ train, const float* __restrict__ levs,
                          float* __restrict__ ow){
  int idx = blockIdx.x*256 + threadIdx.x;   // exactly 833*32*24
  int o = idx % 24;
  int r = idx / 24;
  int b = r & 31;
  int t = r >> 5;
  ow[idx] = train[b*1024 + 168 + t + o] / levs[b*1024 + t + 167];
}

// ---------------- pack whh[1024][256] fp32 -> wp[k4][512] uint4 of 8 halves ----------------
// wp[k4][t] = {w[t][4k4..4k4+3], w[t+512][4k4..4k4+3]} as fp16.
__global__ void pack_k(const float* __restrict__ w, uint4* __restrict__ wp){
  int idx = blockIdx.x*256 + threadIdx.x;   // 32768
  int t = idx & 511, k4 = idx >> 9;
  float4 a = *reinterpret_cast<const float4*>(w + (size_t)t*256 + k4*4);
  float4 b = *reinterpret_cast<const float4*>(w + (size_t)(t+512)*256 + k4*4);
  union { uint4 u; __half h[8]; } r;
  r.h[0]=__float2half(a.x); r.h[1]=__float2half(a.y); r.h[2]=__float2half(a.z); r.h[3]=__float2half(a.w);
  r.h[4]=__float2half(b.x); r.h[5]=__float2half(b.y); r.h[6]=__float2half(b.z); r.h[7]=__float2half(b.w);
  wp[(size_t)k4*512 + t] = r.u;
}

// ---------------- generic fp32 GEMM: C[m][n] = A[map(m)][:K] . W[n][:K] + b1 (+b2), opt tanh
__global__ __launch_bounds__(256) void proj_gemm(
    const float* __restrict__ A, const float* __restrict__ W,
    const float* __restrict__ b1, const float* __restrict__ b2,
    float* __restrict__ C, int Mout, int K, int N, int dil, int act)
{
  __shared__ float As[16][68];
  __shared__ float Bs[16][68];
  int tid = threadIdx.x;
  int tx = tid & 15, ty = tid >> 4;
  int m0 = blockIdx.y << 6, n0 = blockIdx.x << 6;
  int amap[4];
  #pragma unroll
  for (int i = 0; i < 4; ++i){
    int m = m0 + (tid >> 4) + i*16;
    int row;
    if (dil == 0){ row = (m < Mout) ? m : -1; }
    else {
      int rows = dil << 5;
      int j = m / rows;
      int q = m - j*rows;
      int t = j*dil + (q >> 5);
      row = (t < TT) ? ((t << 5) + (q & 31)) : -1;
    }
    amap[i] = row;
  }
  float acc[4][4] = {{0.f,0.f,0.f,0.f},{0.f,0.f,0.f,0.f},{0.f,0.f,0.f,0.f},{0.f,0.f,0.f,0.f}};
  int nkt = (K + 15) >> 4;
  for (int kt = 0; kt < nkt; ++kt){
    int kk = (kt << 4) + (tid & 15);
    bool kin = kk < K;
    #pragma unroll
    for (int i = 0; i < 4; ++i){
      int ml = (tid >> 4) + i*16;
      As[tid & 15][ml] = (kin && amap[i] >= 0) ? A[(size_t)amap[i]*K + kk] : 0.f;
      Bs[tid & 15][ml] = kin ? W[(size_t)(n0 + ml)*K + kk] : 0.f;
    }
    __syncthreads();
    #pragma unroll
    for (int k = 0; k < 16; ++k){
      float4 av = *reinterpret_cast<const float4*>(&As[k][ty << 2]);
      float4 bv = *reinterpret_cast<const float4*>(&Bs[k][tx << 2]);
      float a4[4] = {av.x, av.y, av.z, av.w};
      float b4[4] = {bv.x, bv.y, bv.z, bv.w};
      #pragma unroll
      for (int i = 0; i < 4; ++i)
        #pragma unroll
        for (int j = 0; j < 4; ++j)
          acc[i][j] = fmaf(a4[i], b4[j], acc[i][j]);
    }
    __syncthreads();
  }
  #pragma unroll
  for (int i = 0; i < 4; ++i){
    int m = m0 + (ty << 2) + i;
    if (m >= Mout) continue;
    #pragma unroll
    for (int j = 0; j < 4; ++j){
      int n = n0 + (tx << 2) + j;
      float v = acc[i][j] + b1[n] + (b2 ? b2[n] : 0.f);
      if (act) v = tanhf(v);
      C[(size_t)m*N + n] = v;
    }
  }
}

// ---------------- streamed-weight dilated-LSTM recurrence ----------------
// One WG owns NR whole rows (independent recurrences). Zero cross-WG traffic:
// whh streamed from L2 each step (fp16 packed, 16B/lane), h kept in LDS (fp32),
// c in LDS. Thread t owns gate rows t and t+512 for all NR rows.
// Gates rows: i=[0,256) f=[256,512) g=[512,768) o=[768,1024).
template<int NR>
__global__ __launch_bounds__(512) void srec_k(
    const uint4* __restrict__ wp, const float* __restrict__ Gin,
    float* __restrict__ out, const float* __restrict__ res,
    int nsteps, int d, int rowsTotal)
{
  __shared__ float4 hh[NR][64];     // h[256] per row, float4-tiled to pair with k4
  __shared__ float psum[NR][1024];
  __shared__ float cst[NR][256];
  const int tid = threadIdx.x;
  const int q0 = blockIdx.x*NR;
  for (int e = tid; e < NR*64; e += 512) (&hh[0][0])[e] = make_float4(0.f,0.f,0.f,0.f);
  for (int e = tid; e < NR*256; e += 512) (&cst[0][0])[e] = 0.f;
  __syncthreads();

  for (int step = 0; step < nsteps; ++step){
    // Gin preload (latency hides under matvec)
    float ginA[NR], ginB[NR];
    const float* gbase = Gin + ((size_t)step*rowsTotal + q0)*GDIM;
    #pragma unroll
    for (int rr = 0; rr < NR; ++rr){
      ginA[rr] = gbase[rr*GDIM + tid];
      ginB[rr] = gbase[rr*GDIM + tid + 512];
    }
    float accA0[NR], accA1[NR], accB0[NR], accB1[NR];
    #pragma unroll
    for (int rr = 0; rr < NR; ++rr){ accA0[rr]=0.f; accA1[rr]=0.f; accB0[rr]=0.f; accB1[rr]=0.f; }
    #pragma unroll 4
    for (int k4 = 0; k4 < 64; ++k4){
      uint4 w = wp[(size_t)k4*512 + tid];
      union { unsigned u; __half h[2]; } c0, c1, c2, c3;
      c0.u = w.x; c1.u = w.y; c2.u = w.z; c3.u = w.w;
      float w0 = __half2float(c0.h[0]), w1 = __half2float(c0.h[1]);
      float w2 = __half2float(c1.h[0]), w3 = __half2float(c1.h[1]);
      float w4 = __half2float(c2.h[0]), w5 = __half2float(c2.h[1]);
      float w6 = __half2float(c3.h[0]), w7 = __half2float(c3.h[1]);
      #pragma unroll
      for (int rr = 0; rr < NR; ++rr){
        float4 h4 = hh[rr][k4];
        accA0[rr] = fmaf(w0, h4.x, accA0[rr]);
        accA1[rr] = fmaf(w1, h4.y, accA1[rr]);
        accA0[rr] = fmaf(w2, h4.z, accA0[rr]);
        accA1[rr] = fmaf(w3, h4.w, accA1[rr]);
        accB0[rr] = fmaf(w4, h4.x, accB0[rr]);
        accB1[rr] = fmaf(w5, h4.y, accB1[rr]);
        accB0[rr] = fmaf(w6, h4.z, accB0[rr]);
        accB1[rr] = fmaf(w7, h4.w, accB1[rr]);
      }
    }
    #pragma unroll
    for (int rr = 0; rr < NR; ++rr){
      psum[rr][tid]       = accA0[rr] + accA1[rr] + ginA[rr];
      psum[rr][tid + 512] = accB0[rr] + accB1[rr] + ginB[rr];
    }
    __syncthreads();
    if (tid < 256){
      #pragma unroll
      for (int rr = 0; rr < NR; ++rr){
        float iv = psum[rr][tid];
        float fv = psum[rr][tid + 256];
        float gv = psum[rr][tid + 512];
        float ov = psum[rr][tid + 768];
        float c = cst[rr][tid];
        c = sigm(fv)*c + sigm(iv)*tanhf(gv);
        float h = sigm(ov)*tanhf(c);
        cst[rr][tid] = c;
        (&hh[rr][0].x)[tid] = h;
        int q = q0 + rr;
        int tg = step*d + (q >> 5);
        if (tg < TT){
          size_t oi = ((size_t)tg*32 + (q & 31))*256 + tid;
          out[oi] = res ? (h + res[oi]) : h;
        }
      }
    }
    __syncthreads();
  }
}

// ---------------- scoring head: pred[m][24] = xt[m][:] . sc_w[n][:] + sc_b ----------------
__global__ __launch_bounds__(256) void sc_head(const float* __restrict__ xt, const float* __restrict__ w,
                        const float* __restrict__ bias, float* __restrict__ outp, int M){
  __shared__ float arow[8][256];
  int m0 = blockIdx.x << 3;
  int tid = threadIdx.x;
  #pragma unroll
  for (int i = 0; i < 8; ++i){
    int e = tid + (i << 8);
    int r = e >> 8, k = e & 255;
    arow[r][k] = (m0 + r < M) ? xt[(size_t)(m0 + r)*256 + k] : 0.f;
  }
  __syncthreads();
  int r = tid >> 5, n = tid & 31;
  if (n < 24 && (m0 + r) < M){
    float acc = bias[n];
    const float* wr = w + n*256;
    #pragma unroll 8
    for (int k = 0; k < 256; ++k) acc = fmaf(arow[r][k], wr[k], acc);
    outp[(size_t)(m0 + r)*24 + n] = acc;
  }
}

extern "C" void kernel_launch(void* const* d_in, const int* in_sizes, int n_in,
                              void* d_out, int out_size, void* d_ws, size_t ws_size,
                              hipStream_t stream){
  const float* train = (const float*)d_in[0];
  const float* ism   = (const float*)d_in[4];
  const float* wih[4] = {(const float*)d_in[5], (const float*)d_in[9], (const float*)d_in[13], (const float*)d_in[17]};
  const float* whh[4] = {(const float*)d_in[6], (const float*)d_in[10], (const float*)d_in[14], (const float*)d_in[18]};
  const float* bih[4] = {(const float*)d_in[7], (const float*)d_in[11], (const float*)d_in[15], (const float*)d_in[19]};
  const float* bhh[4] = {(const float*)d_in[8], (const float*)d_in[12], (const float*)d_in[16], (const float*)d_in[20]};
  const float* nl_w = (const float*)d_in[21];
  const float* nl_b = (const float*)d_in[22];
  const float* sc_w = (const float*)d_in[23];
  const float* sc_b = (const float*)d_in[24];
  float* out = (float*)d_out;

  float* ws = (float*)d_ws;
  size_t off = 0;
  float* levs = ws + off;   off += 32768;
  uint4* wpk[4];
  for (int l = 0; l < 4; ++l){ wpk[l] = (uint4*)(ws + off); off += 131072; }  // 512KB each
  float* x0 = ws + off;     off += (size_t)26656*168;
  float* G  = ws + off;     off += (size_t)28672*1024;
  float* h0 = ws + off;     off += (size_t)26656*256;
  float* h1 = ws + off;     off += (size_t)26656*256;
  float* h2 = ws + off;     off += (size_t)26656*256;
  (void)ws_size; (void)in_sizes; (void)n_in; (void)out_size;

  levels_k<<<1, 64, 0, stream>>>(train, ism, levs);
  win_x_k<<<17493, 256, 0, stream>>>(train, levs, x0);
  win_out_k<<<2499, 256, 0, stream>>>(train, levs, out + 639744);
  for (int l = 0; l < 4; ++l)
    pack_k<<<128, 256, 0, stream>>>(whh[l], wpk[l]);

  // layer 0 (d=1): 833 steps, 32 rows -> 32 WGs x 1 row
  proj_gemm<<<dim3(16,417), 256, 0, stream>>>(x0, wih[0], bih[0], bhh[0], G, 26656, 168, 1024, 0, 0);
  srec_k<1><<<32, 512, 0, stream>>>(wpk[0], G, h0, nullptr, 833, 1, 32);
  // layer 1 (d=4): 209 steps, 128 rows -> 128 WGs x 1 row
  proj_gemm<<<dim3(16,418), 256, 0, stream>>>(h0, wih[1], bih[1], bhh[1], G, 26752, 256, 1024, 4, 0);
  srec_k<1><<<128, 512, 0, stream>>>(wpk[1], G, h1, nullptr, 209, 4, 128);
  // layer 2 (d=16): 53 steps, 512 rows -> 256 WGs x 2 rows
  proj_gemm<<<dim3(16,424), 256, 0, stream>>>(h1, wih[2], bih[2], bhh[2], G, 27136, 256, 1024, 16, 0);
  srec_k<2><<<256, 512, 0, stream>>>(wpk[2], G, h2, nullptr, 53, 16, 512);
  // layer 3 (d=64): 14 steps, 2048 rows -> 256 WGs x 8 rows; residual h1; out overwrites h2
  proj_gemm<<<dim3(16,448), 256, 0, stream>>>(h2, wih[3], bih[3], bhh[3], G, 28672, 256, 1024, 64, 0);
  srec_k<8><<<256, 512, 0, stream>>>(wpk[3], G, h2, h1, 14, 64, 2048);
  // nonlinear dense: xt = tanh(xf @ nl_w.T + nl_b)  (reuse h0)
  proj_gemm<<<dim3(4,417), 256, 0, stream>>>(h2, nl_w, nl_b, nullptr, h0, 26656, 256, 256, 0, 1);
  // scoring head -> pred (first half of d_out)
  sc_head<<<3332, 256, 0, stream>>>(h0, sc_w, sc_b, out, 26656);
}